// Round 10
// baseline (190.910 us; speedup 1.0000x reference)
//
#include <hip/hip_runtime.h>
#include <hip/hip_bf16.h>

typedef __bf16 bf16_t;
typedef __bf16 bf16x8 __attribute__((ext_vector_type(8)));
typedef __bf16 bf16x4 __attribute__((ext_vector_type(4)));
typedef float f32x4 __attribute__((ext_vector_type(4)));

#define MFMA16(a, b, c) __builtin_amdgcn_mfma_f32_16x16x32_bf16((a), (b), (c), 0, 0, 0)

__device__ __forceinline__ f32x4 v4zero() {
  f32x4 z = {0.f, 0.f, 0.f, 0.f};
  return z;
}
__device__ __forceinline__ f32x4 v4splat(float v) {
  f32x4 z = {v, v, v, v};
  return z;
}
__device__ __forceinline__ f32x4 v4max(f32x4 a, f32x4 b) {
  f32x4 r;
#pragma unroll
  for (int i = 0; i < 4; ++i) r[i] = fmaxf(a[i], b[i]);
  return r;
}

// window-partition row mapping: m = win*512 + t  ->  row in x [B*4096]
__device__ __forceinline__ int xrow_of(int m) {
  int win = m >> 9, t = m & 511;
  int b = win >> 3, d1 = (win >> 2) & 1, h1 = (win >> 1) & 1, w1 = win & 1;
  int d2 = t >> 6, h2 = (t >> 3) & 7, w2 = t & 7;
  return (b << 12) | ((d1 * 8 + d2) << 8) | ((h1 * 8 + h2) << 4) | (w1 * 8 + w2);
}

// ---------------- kernel 1: QKV projection + window partition ----------------
// grid (128, 9), block 256. C-tile 128x128, 4 waves of 64x64.
// Q,K stored [32][6][512][64]; V stored transposed [32][6][64][512].
__global__ __launch_bounds__(256) void qkv_kernel(
    const float* __restrict__ x, const float* __restrict__ w,
    const float* __restrict__ bias, bf16_t* __restrict__ qg,
    bf16_t* __restrict__ kg, bf16_t* __restrict__ vtg) {
  __shared__ __align__(16) bf16_t At[128][40];
  __shared__ __align__(16) bf16_t Bt[128][40];
  const int tid = threadIdx.x;
  const int lane = tid & 63, wv = tid >> 6;
  const int m0 = blockIdx.x * 128, n0 = blockIdx.y * 128;

  const int arow = tid >> 1, aseg = tid & 1;
  const float* asrc = x + (size_t)xrow_of(m0 + arow) * 384 + aseg * 16;
  const int bn = tid & 127, bks = (tid >> 7) * 16;

  const int wr = (wv >> 1) * 64, wc = (wv & 1) * 64;
  const int lr = lane & 15, lk = (lane >> 4) * 8;

  f32x4 acc[4][4];
#pragma unroll
  for (int fr = 0; fr < 4; ++fr)
#pragma unroll
    for (int fc = 0; fc < 4; ++fc) acc[fr][fc] = v4zero();

  for (int kt = 0; kt < 12; ++kt) {
    f32x4 av0 = *(const f32x4*)(asrc + kt * 32);
    f32x4 av1 = *(const f32x4*)(asrc + kt * 32 + 4);
    f32x4 av2 = *(const f32x4*)(asrc + kt * 32 + 8);
    f32x4 av3 = *(const f32x4*)(asrc + kt * 32 + 12);
    bf16x8 a0, a1;
#pragma unroll
    for (int i = 0; i < 4; ++i) {
      a0[i] = (bf16_t)av0[i];
      a0[4 + i] = (bf16_t)av1[i];
      a1[i] = (bf16_t)av2[i];
      a1[4 + i] = (bf16_t)av3[i];
    }
    bf16x8 b0, b1;
#pragma unroll
    for (int i = 0; i < 8; ++i)
      b0[i] = (bf16_t)w[(size_t)(kt * 32 + bks + i) * 1152 + n0 + bn];
#pragma unroll
    for (int i = 0; i < 8; ++i)
      b1[i] = (bf16_t)w[(size_t)(kt * 32 + bks + 8 + i) * 1152 + n0 + bn];
    *(bf16x8*)&At[arow][aseg * 16] = a0;
    *(bf16x8*)&At[arow][aseg * 16 + 8] = a1;
    *(bf16x8*)&Bt[bn][bks] = b0;
    *(bf16x8*)&Bt[bn][bks + 8] = b1;
    __syncthreads();
    bf16x8 af[4], bfv[4];
#pragma unroll
    for (int fr = 0; fr < 4; ++fr) af[fr] = *(const bf16x8*)&At[wr + fr * 16 + lr][lk];
#pragma unroll
    for (int fc = 0; fc < 4; ++fc) bfv[fc] = *(const bf16x8*)&Bt[wc + fc * 16 + lr][lk];
#pragma unroll
    for (int fr = 0; fr < 4; ++fr)
#pragma unroll
      for (int fc = 0; fc < 4; ++fc)
        acc[fr][fc] = MFMA16(af[fr], bfv[fc], acc[fr][fc]);
    __syncthreads();
  }

  const int colb = n0 + wc;
  const int type = colb >= 768 ? 2 : (colb >= 384 ? 1 : 0);
#pragma unroll
  for (int fc = 0; fc < 4; ++fc) {
    const int col = colb + fc * 16 + lr;
    const float bc = bias[col];
    const int cc = col - type * 384;
    const int hh = cc >> 6, c = cc & 63;
#pragma unroll
    for (int fr = 0; fr < 4; ++fr) {
      const int m = m0 + wr + fr * 16 + (lane >> 4) * 4;
      const int win = m >> 9, t = m & 511;
      if (type == 2) {
        bf16x4 pk;
#pragma unroll
        for (int r = 0; r < 4; ++r) pk[r] = (bf16_t)(acc[fr][fc][r] + bc);
        *(bf16x4*)(vtg + ((size_t)(win * 6 + hh) * 64 + c) * 512 + t) = pk;
      } else {
        bf16_t* dst = (type == 0 ? qg : kg) + ((size_t)(win * 6 + hh) * 512 + t) * 64 + c;
#pragma unroll
        for (int r = 0; r < 4; ++r) dst[(size_t)r * 64] = (bf16_t)(acc[fr][fc][r] + bc);
      }
    }
  }
}

// ---------------- kernel 2: windowed MFMA attention, decomposed rel-pos -----
// grid (4 qtiles, 6 heads, 32 windows), block 256 (4 waves x 32 q-rows).
__global__ __launch_bounds__(256) void attn_kernel(
    const bf16_t* __restrict__ qg, const bf16_t* __restrict__ kg,
    const bf16_t* __restrict__ vtg, const float* __restrict__ rpx,
    const float* __restrict__ rpy, const float* __restrict__ rpz,
    bf16_t* __restrict__ ao) {
  __shared__ __align__(16) float rT[3][8][132];      // [axis][key-coord][block row]
  __shared__ __align__(16) bf16_t pbuf[4][32][72];   // per-wave P transpose
  const int tid = threadIdx.x, lane = tid & 63, wv = tid >> 6;
  const int qt = blockIdx.x, hh = blockIdx.y, win = blockIdx.z;
  const int wh = win * 6 + hh;
  const bf16_t* Qb = qg + (size_t)wh * 32768;
  const bf16_t* Kb = kg + (size_t)wh * 32768;
  const bf16_t* Vb = vtg + (size_t)wh * 32768;  // transposed [64][512]

  // bias tables: rT[axis][k][row] = q_row . R_axis[qpos-k+7]
  for (int i = 0; i < 12; ++i) {
    int flat = tid * 12 + i;  // 3072 = 128 rows * 24 dots
    int row = flat / 24;
    int idx = flat - row * 24;
    int axis = idx >> 3, kk = idx & 7;
    int tq = qt * 128 + row;
    int qp = (axis == 0) ? (tq >> 6) : (axis == 1) ? ((tq >> 3) & 7) : (tq & 7);
    const float* R = ((axis == 0) ? rpx : (axis == 1) ? rpy : rpz) + (qp - kk + 7) * 64;
    const bf16_t* Qr = Qb + (size_t)tq * 64;
    float s = 0.f;
    for (int j8 = 0; j8 < 8; ++j8) {
      bf16x8 a = *(const bf16x8*)(Qr + j8 * 8);
      f32x4 r0 = *(const f32x4*)(R + j8 * 8);
      f32x4 r1 = *(const f32x4*)(R + j8 * 8 + 4);
#pragma unroll
      for (int j = 0; j < 4; ++j) s += (float)a[j] * r0[j] + (float)a[4 + j] * r1[j];
    }
    rT[axis][kk][row] = s;
  }
  __syncthreads();

  const int lr = lane & 15, lg = lane >> 4;
  const int qrow0 = qt * 128 + wv * 32;

  bf16x8 aq[2][2];
#pragma unroll
  for (int fr = 0; fr < 2; ++fr)
#pragma unroll
    for (int ks = 0; ks < 2; ++ks)
      aq[fr][ks] = *(const bf16x8*)(Qb + (size_t)(qrow0 + fr * 16 + lr) * 64 + ks * 32 + lg * 8);

  const int rb0 = wv * 32 + lg * 4;
  f32x4 byz[2][4];
#pragma unroll
  for (int fr = 0; fr < 2; ++fr) {
    f32x4 rz = *(const f32x4*)&rT[2][lane & 7][rb0 + fr * 16];
#pragma unroll
    for (int fc = 0; fc < 4; ++fc) {
      f32x4 ry = *(const f32x4*)&rT[1][fc * 2 + ((lane >> 3) & 1)][rb0 + fr * 16];
      byz[fr][fc] = ry + rz;
    }
  }

  f32x4 mrow[2], lrow[2], oacc[2][4];
#pragma unroll
  for (int fr = 0; fr < 2; ++fr) {
    mrow[fr] = v4splat(-1e30f);
    lrow[fr] = v4zero();
#pragma unroll
    for (int fc = 0; fc < 4; ++fc) oacc[fr][fc] = v4zero();
  }

  for (int kt = 0; kt < 8; ++kt) {
    bf16x8 bk[4][2];
#pragma unroll
    for (int fc = 0; fc < 4; ++fc)
#pragma unroll
      for (int ks = 0; ks < 2; ++ks)
        bk[fc][ks] = *(const bf16x8*)(Kb + (size_t)(kt * 64 + fc * 16 + lr) * 64 + ks * 32 + lg * 8);

    f32x4 sb[2][4];
#pragma unroll
    for (int fr = 0; fr < 2; ++fr) {
      f32x4 rx = *(const f32x4*)&rT[0][kt][rb0 + fr * 16];
#pragma unroll
      for (int fc = 0; fc < 4; ++fc) {
        f32x4 s = MFMA16(aq[fr][0], bk[fc][0], v4zero());
        s = MFMA16(aq[fr][1], bk[fc][1], s);
        sb[fr][fc] = s * 0.125f + rx + byz[fr][fc];
      }
    }

#pragma unroll
    for (int fr = 0; fr < 2; ++fr) {
      f32x4 tm = sb[fr][0];
#pragma unroll
      for (int fc = 1; fc < 4; ++fc) tm = v4max(tm, sb[fr][fc]);
#pragma unroll
      for (int d = 1; d < 16; d <<= 1) {
#pragma unroll
        for (int i = 0; i < 4; ++i) tm[i] = fmaxf(tm[i], __shfl_xor(tm[i], d));
      }
      f32x4 mnew = v4max(mrow[fr], tm);
      f32x4 corr;
#pragma unroll
      for (int i = 0; i < 4; ++i) corr[i] = __expf(mrow[fr][i] - mnew[i]);
      mrow[fr] = mnew;
      f32x4 rsum = v4zero();
#pragma unroll
      for (int fc = 0; fc < 4; ++fc) {
#pragma unroll
        for (int i = 0; i < 4; ++i) {
          float p = __expf(sb[fr][fc][i] - mnew[i]);
          sb[fr][fc][i] = p;
          rsum[i] += p;
        }
      }
#pragma unroll
      for (int d = 1; d < 16; d <<= 1) {
#pragma unroll
        for (int i = 0; i < 4; ++i) rsum[i] += __shfl_xor(rsum[i], d);
      }
      lrow[fr] = lrow[fr] * corr + rsum;
#pragma unroll
      for (int fc = 0; fc < 4; ++fc) oacc[fr][fc] *= corr;
#pragma unroll
      for (int fc = 0; fc < 4; ++fc)
#pragma unroll
        for (int i = 0; i < 4; ++i)
          pbuf[wv][fr * 16 + lg * 4 + i][fc * 16 + lr] = (bf16_t)sb[fr][fc][i];
    }

    bf16x8 pa[2][2], bv[4][2];
#pragma unroll
    for (int fr = 0; fr < 2; ++fr)
#pragma unroll
      for (int ks = 0; ks < 2; ++ks)
        pa[fr][ks] = *(const bf16x8*)&pbuf[wv][fr * 16 + lr][ks * 32 + lg * 8];
#pragma unroll
    for (int fc = 0; fc < 4; ++fc)
#pragma unroll
      for (int ks = 0; ks < 2; ++ks)
        bv[fc][ks] = *(const bf16x8*)(Vb + (size_t)(fc * 16 + lr) * 512 + kt * 64 + ks * 32 + lg * 8);
#pragma unroll
    for (int fr = 0; fr < 2; ++fr)
#pragma unroll
      for (int fc = 0; fc < 4; ++fc) {
        oacc[fr][fc] = MFMA16(pa[fr][0], bv[fc][0], oacc[fr][fc]);
        oacc[fr][fc] = MFMA16(pa[fr][1], bv[fc][1], oacc[fr][fc]);
      }
  }

#pragma unroll
  for (int fr = 0; fr < 2; ++fr) {
    f32x4 linv;
#pragma unroll
    for (int i = 0; i < 4; ++i) linv[i] = 1.0f / lrow[fr][i];
#pragma unroll
    for (int fc = 0; fc < 4; ++fc) {
      size_t base = ((size_t)win * 512 + qrow0 + fr * 16 + lg * 4) * 384 + hh * 64 + fc * 16 + lr;
#pragma unroll
      for (int i = 0; i < 4; ++i)
        ao[base + (size_t)i * 384] = (bf16_t)(oacc[fr][fc][i] * linv[i]);
    }
  }
}

// ---------------- kernel 3: output projection -> FLOAT32 out ----------------
__global__ __launch_bounds__(256) void proj_kernel(
    const bf16_t* __restrict__ ain, const float* __restrict__ w,
    const float* __restrict__ bias, float* __restrict__ out) {
  __shared__ __align__(16) bf16_t At[128][40];
  __shared__ __align__(16) bf16_t Bt[128][40];
  const int tid = threadIdx.x;
  const int lane = tid & 63, wv = tid >> 6;
  const int m0 = blockIdx.x * 128, n0 = blockIdx.y * 128;

  const int arow = tid >> 1, aseg = tid & 1;
  const bf16_t* asrc = ain + (size_t)(m0 + arow) * 384 + aseg * 16;
  const int bn = tid & 127, bks = (tid >> 7) * 16;

  const int wr = (wv >> 1) * 64, wc = (wv & 1) * 64;
  const int lr = lane & 15, lk = (lane >> 4) * 8;

  f32x4 acc[4][4];
#pragma unroll
  for (int fr = 0; fr < 4; ++fr)
#pragma unroll
    for (int fc = 0; fc < 4; ++fc) acc[fr][fc] = v4zero();

  for (int kt = 0; kt < 12; ++kt) {
    bf16x8 a0 = *(const bf16x8*)(asrc + kt * 32);
    bf16x8 a1 = *(const bf16x8*)(asrc + kt * 32 + 8);
    bf16x8 b0, b1;
#pragma unroll
    for (int i = 0; i < 8; ++i)
      b0[i] = (bf16_t)w[(size_t)(kt * 32 + bks + i) * 384 + n0 + bn];
#pragma unroll
    for (int i = 0; i < 8; ++i)
      b1[i] = (bf16_t)w[(size_t)(kt * 32 + bks + 8 + i) * 384 + n0 + bn];
    *(bf16x8*)&At[arow][aseg * 16] = a0;
    *(bf16x8*)&At[arow][aseg * 16 + 8] = a1;
    *(bf16x8*)&Bt[bn][bks] = b0;
    *(bf16x8*)&Bt[bn][bks + 8] = b1;
    __syncthreads();
    bf16x8 af[4], bfv[4];
#pragma unroll
    for (int fr = 0; fr < 4; ++fr) af[fr] = *(const bf16x8*)&At[wr + fr * 16 + lr][lk];
#pragma unroll
    for (int fc = 0; fc < 4; ++fc) bfv[fc] = *(const bf16x8*)&Bt[wc + fc * 16 + lr][lk];
#pragma unroll
    for (int fr = 0; fr < 4; ++fr)
#pragma unroll
      for (int fc = 0; fc < 4; ++fc)
        acc[fr][fc] = MFMA16(af[fr], bfv[fc], acc[fr][fc]);
    __syncthreads();
  }

#pragma unroll
  for (int fc = 0; fc < 4; ++fc) {
    const int col = n0 + wc + fc * 16 + lr;
    const float bc = bias[col];
#pragma unroll
    for (int fr = 0; fr < 4; ++fr) {
      const int m = m0 + wr + fr * 16 + (lane >> 4) * 4;
#pragma unroll
      for (int r = 0; r < 4; ++r)
        out[(size_t)xrow_of(m + r) * 384 + col] = acc[fr][fc][r] + bc;  // f32 store
    }
  }
}

extern "C" void kernel_launch(void* const* d_in, const int* in_sizes, int n_in,
                              void* d_out, int out_size, void* d_ws, size_t ws_size,
                              hipStream_t stream) {
  (void)in_sizes; (void)n_in; (void)out_size;
  const float* x = (const float*)d_in[0];
  const float* qkv_w = (const float*)d_in[1];
  const float* qkv_b = (const float*)d_in[2];
  const float* proj_w = (const float*)d_in[3];
  const float* proj_b = (const float*)d_in[4];
  const float* rpx = (const float*)d_in[5];
  const float* rpy = (const float*)d_in[6];
  const float* rpz = (const float*)d_in[7];
  float* out = (float*)d_out;  // reference output dtype is float32

  const size_t NE = 6291456;  // 32*6*512*64 = 16384*384
  if (ws_size < NE * 4 * sizeof(bf16_t)) return;  // q,k,vt,attnout (bf16)
  bf16_t* qg = (bf16_t*)d_ws;
  bf16_t* kg = qg + NE;
  bf16_t* vtg = kg + NE;
  bf16_t* ao = vtg + NE;

  qkv_kernel<<<dim3(128, 9), 256, 0, stream>>>(x, qkv_w, qkv_b, qg, kg, vtg);
  attn_kernel<<<dim3(4, 6, 32), 256, 0, stream>>>(qg, kg, vtg, rpx, rpy, rpz, ao);
  proj_kernel<<<dim3(128, 3), 256, 0, stream>>>(ao, proj_w, proj_b, out);
}